// Round 2
// baseline (214.775 us; speedup 1.0000x reference)
//
#include <hip/hip_runtime.h>
#include <math.h>

#define THREADS 256   // 8 threads per token; thread = one expert group
#define TPB 32        // tokens per block
#define NEXP 256
#define EPS_S 2.0e-6f // single-score margins (f32 score err <= ~4e-7, 5x safety)
#define EPS_G 4.0e-6f // group-sum margins

// ---- fast f32 sigmoid: hw v_exp_f32 + fast divide ----
__device__ __forceinline__ float fsigmoid(float x) {
    float e = __expf(-x);
    return __fdividef(1.0f, 1.0f + e);
}

// ---- cheap near-exact f64 sigmoid (rare paths only): Taylor exp + NR division ----
__device__ __forceinline__ double dsigmoid(float xf) {
    xf = fminf(fmaxf(xf, -500.0f), 500.0f);
    double x = (double)xf;
    double t = x * -1.4426950408889634074;           // -x*log2(e)
    double n = floor(t + 0.5);
    int ni = (int)n;
    double u = (t - n) * 0.69314718055994530942;
    double pp = 2.08767569878680990e-9;
    pp = fma(pp, u, 2.50521083854417188e-8);
    pp = fma(pp, u, 2.75573192239858907e-7);
    pp = fma(pp, u, 2.75573192239858883e-6);
    pp = fma(pp, u, 2.48015873015873016e-5);
    pp = fma(pp, u, 1.98412698412698413e-4);
    pp = fma(pp, u, 1.38888888888888889e-3);
    pp = fma(pp, u, 8.33333333333333333e-3);
    pp = fma(pp, u, 4.16666666666666667e-2);
    pp = fma(pp, u, 1.66666666666666667e-1);
    pp = fma(pp, u, 0.5);
    pp = fma(pp, u, 1.0);
    pp = fma(pp, u, 1.0);
    double sc = __longlong_as_double((long long)(1023 + ni) << 52);
    double e = pp * sc;                              // exp(-x)
    double w = 1.0 + e;
    double y = (double)__fdividef(1.0f, (float)w);
    y = fma(y, fma(-w, y, 1.0), y);
    y = fma(y, fma(-w, y, 1.0), y);
    return y;
}

// f64 8-deep sorted insert (cold path)
#define DINS(cc, ee) do {                                                \
    double _d=(cc); int _e=(ee);                                         \
    if (_d > s7) {                                                       \
        bool _b0=_d>s0,_b1=_d>s1,_b2=_d>s2,_b3=_d>s3,_b4=_d>s4,          \
             _b5=_d>s5,_b6=_d>s6;                                        \
        s7=_b6?s6:_d;           c7=_b6?c6:_e;                            \
        s6=_b5?s5:(_b6?_d:s6);  c6=_b5?c5:(_b6?_e:c6);                   \
        s5=_b4?s4:(_b5?_d:s5);  c5=_b4?c4:(_b5?_e:c5);                   \
        s4=_b3?s3:(_b4?_d:s4);  c4=_b3?c3:(_b4?_e:c4);                   \
        s3=_b2?s2:(_b3?_d:s3);  c3=_b2?c2:(_b3?_e:c3);                   \
        s2=_b1?s1:(_b2?_d:s2);  c2=_b1?c1:(_b2?_e:c2);                   \
        s1=_b0?s0:(_b1?_d:s1);  c1=_b0?c0:(_b1?_e:c1);                   \
        s0=_b0?_d:s0;           c0=_b0?_e:c0;                            \
    } } while (0)

// ---- value-only compare-exchange primitives ----
// f32 ties never determine the output: any adjacent tie in the final 9-list
// gives margin 0 < EPS_S -> flagB -> f64 re-resolve from the candidate SET.
// (The m8/10th boundary tie-hole is identical to the MINS version that has
// passed verification; semantics class unchanged.)
// CEV: descending compare-exchange (larger value -> a). 1 cmp + 4 cndmask.
#define CEV(av, ai, bv, bi) do {                                         \
    bool _s = (bv) > (av);                                               \
    float _tv = (av); int _ti = (ai);                                    \
    (av) = _s ? (bv) : (av); (ai) = _s ? (bi) : (ai);                    \
    (bv) = _s ? _tv : (bv); (bi) = _s ? _ti : (bi);                      \
} while (0)
// VMX: a := max(a, b) by value (ties keep a). 1 cmp + 2 cndmask.
#define VMX(av, ai, bv, bi) do {                                         \
    bool _s = (bv) > (av);                                               \
    (av) = _s ? (bv) : (av); (ai) = _s ? (bi) : (ai);                    \
} while (0)

// Batcher odd-even mergesort network for 8 elements, descending. 19 CE.
#define SORT8(v0,i0,v1,i1,v2,i2,v3,i3,v4,i4,v5,i5,v6,i6,v7,i7) do {      \
    CEV(v0,i0,v1,i1); CEV(v2,i2,v3,i3); CEV(v4,i4,v5,i5); CEV(v6,i6,v7,i7); \
    CEV(v0,i0,v2,i2); CEV(v1,i1,v3,i3); CEV(v4,i4,v6,i6); CEV(v5,i5,v7,i7); \
    CEV(v1,i1,v2,i2); CEV(v5,i5,v6,i6);                                  \
    CEV(v0,i0,v4,i4); CEV(v1,i1,v5,i5); CEV(v2,i2,v6,i6); CEV(v3,i3,v7,i7); \
    CEV(v2,i2,v4,i4); CEV(v3,i3,v5,i5);                                  \
    CEV(v1,i1,v2,i2); CEV(v3,i3,v4,i4); CEV(v5,i5,v6,i6);                \
} while (0)

// valley (dec-then-inc) 9-sequence in m0..m8 -> sorted descending. 13 CE.
// Same network as the round-1 validated XMERGE_B cleanup.
#define CLEAN9 do {                                                      \
    CEV(m0,n0,m8,n8);                                                    \
    CEV(m1,n1,m5,n5); CEV(m2,n2,m6,n6); CEV(m3,n3,m7,n7); CEV(m4,n4,m8,n8); \
    CEV(m1,n1,m3,n3); CEV(m2,n2,m4,n4); CEV(m5,n5,m7,n7); CEV(m6,n6,m8,n8); \
    CEV(m1,n1,m2,n2); CEV(m3,n3,m4,n4); CEV(m5,n5,m6,n6); CEV(m7,n7,m8,n8); \
} while (0)

// Merge my sorted-desc 9-list with xor-partner's via the bitonic identity:
//   t[i] = max(a[i], b[8-i]) is the top-9 multiset, as a "valley" sequence.
#define XMERGE_B(d) do {                                                 \
    float q0=__shfl_xor(m0,d,64), q1=__shfl_xor(m1,d,64),                \
          q2=__shfl_xor(m2,d,64), q3=__shfl_xor(m3,d,64),                \
          q4=__shfl_xor(m4,d,64), q5=__shfl_xor(m5,d,64),                \
          q6=__shfl_xor(m6,d,64), q7=__shfl_xor(m7,d,64),                \
          q8=__shfl_xor(m8,d,64);                                        \
    int   r0=__shfl_xor(n0,d,64), r1=__shfl_xor(n1,d,64),                \
          r2=__shfl_xor(n2,d,64), r3=__shfl_xor(n3,d,64),                \
          r4=__shfl_xor(n4,d,64), r5=__shfl_xor(n5,d,64),                \
          r6=__shfl_xor(n6,d,64), r7=__shfl_xor(n7,d,64),                \
          r8=__shfl_xor(n8,d,64);                                        \
    VMX(m0,n0,q8,r8); VMX(m1,n1,q7,r7); VMX(m2,n2,q6,r6);                \
    VMX(m3,n3,q5,r5); VMX(m4,n4,q4,r4); VMX(m5,n5,q3,r3);                \
    VMX(m6,n6,q2,r2); VMX(m7,n7,q1,r1); VMX(m8,n8,q0,r0);                \
    CLEAN9;                                                              \
} while (0)

__device__ __forceinline__ float4 shfl4(float4 v, int src) {
    float4 r;
    r.x = __shfl(v.x, src, 64);
    r.y = __shfl(v.y, src, 64);
    r.z = __shfl(v.z, src, 64);
    r.w = __shfl(v.w, src, 64);
    return r;
}

__global__ __launch_bounds__(THREADS, 6)
void noauxtc_router_kernel(const float* __restrict__ logits,
                           const float* __restrict__ bias,
                           float* __restrict__ out,   // [T*8] weights, [T*8] ids-as-f32
                           int T)
{
    __shared__ __align__(16) float bias_sh[NEXP];      // 1 KiB — only LDS use

    const int tid   = threadIdx.x;
    const int h     = tid & 7;            // owned group (experts 32h..32h+31)
    const int p     = tid >> 3;           // token-in-block
    const int tok0  = blockIdx.x * TPB;
    const int token = tok0 + p;
    const int lane  = tid & 63;
    const int base  = lane & 56;          // first lane of this token's octet

    // ---- issue own-group loads early: one 128B line/thread, 8x b128 ----
    const float4* lg4 = (const float4*)logits;
    float4 st[8];
    #pragma unroll
    for (int k = 0; k < 8; ++k)
        st[k] = lg4[(size_t)token * 64 + h * 8 + k];

    bias_sh[tid] = bias[tid];             // THREADS == NEXP
    __syncthreads();                      // only barrier

    const float4* bias4 = (const float4*)bias_sh;

    // ---------------- pass 1: corrected scores in-place + own-group top-2 ----------------
    float g1 = -3e38f, g2 = -3e38f;       // group top-2 values (ids not needed)
    #pragma unroll
    for (int q = 0; q < 8; ++q) {
        float4 bb = bias4[h * 8 + q];     // broadcast across octets: free
        float4 c;
        c.x = fsigmoid(st[q].x) + bb.x;
        c.y = fsigmoid(st[q].y) + bb.y;
        c.z = fsigmoid(st[q].z) + bb.z;
        c.w = fsigmoid(st[q].w) + bb.w;
        st[q] = c;                        // overwrite logits with scores
        float h1 = fmaxf(c.x, c.y), l1 = fminf(c.x, c.y);
        float h2 = fmaxf(c.z, c.w), l2 = fminf(c.z, c.w);
        float t1 = fmaxf(h1, h2);
        float t2 = fmaxf(fminf(h1, h2), fmaxf(l1, l2));   // top-2 of the quad
        g2 = fmaxf(fminf(g1, t1), fmaxf(g2, t2));         // merge sorted pairs
        g1 = fmaxf(g1, t1);
    }
    float gs = g1 + g2;                   // group score = top-2 sum

    // ---------------- all 8 group scores via bpermute gather ----------------
    float gsv[8];
    #pragma unroll
    for (int g = 0; g < 8; ++g) gsv[g] = __shfl(gs, base + g, 64);

    // ---------------- top-4 groups (rank count, lower idx wins) + margin ----------------
    int selmask = 0; float val4 = 0.f, val5 = 0.f;
    #pragma unroll
    for (int a = 0; a < 8; ++a) {
        int rk = 0;
        #pragma unroll
        for (int b = 0; b < 8; ++b) {
            if (b == a) continue;
            bool beat = (b < a) ? (gsv[b] >= gsv[a]) : (gsv[b] > gsv[a]);
            rk += beat ? 1 : 0;
        }
        selmask |= (rk < 4) ? (1 << a) : 0;
        val4 = (rk == 3) ? gsv[a] : val4;
        val5 = (rk == 4) ? gsv[a] : val5;
    }

    // ---- flagA: ambiguous 4th vs 5th group -> pure-f64 re-rank (cold; logits from global) ----
    if (__builtin_expect(val4 - val5 < EPS_G, 0)) {
        // each thread: own group's f64 top-2 sum (uniform condition per octet)
        double a1 = -1e300, a2 = -1e300;
        const float* lgp = logits + (size_t)token * 256 + h * 32;
        #pragma unroll 1
        for (int k = 0; k < 32; ++k) {
            double c = dsigmoid(lgp[k]) + (double)bias_sh[h * 32 + k];
            a2 = fmax(a2, fmin(a1, c)); a1 = fmax(a1, c);
        }
        double gdo = a1 + a2;
        double gd[8];
        #pragma unroll
        for (int g = 0; g < 8; ++g) gd[g] = __shfl(gdo, base + g, 64);
        int sm = 0;
        #pragma unroll
        for (int a = 0; a < 8; ++a) {
            int rk = 0;
            #pragma unroll
            for (int b = 0; b < 8; ++b) {
                if (b == a) continue;
                bool beat = (b < a) ? (gd[b] >= gd[a]) : (gd[b] > gd[a]);
                rk += beat ? 1 : 0;
            }
            sm |= (rk < 4) ? (1 << a) : 0;
        }
        selmask = sm;
    }

    // ---------------- map thread -> (selected group, half) ----------------
    const int want = h >> 1;              // 0..3 : which selected group (ascending)
    int g = 0, cnt = 0;
    #pragma unroll
    for (int a = 0; a < 8; ++a) {
        bool s = (selmask >> a) & 1;
        g = (s && (cnt == want)) ? a : g;
        cnt += s ? 1 : 0;
    }
    const int hf  = h & 1;                // which 16-element half of the group
    const int src = base + g;             // lane holding that group's scores

    // ---- gather 16 scores via shfl (both halves; static reg indices; convergent) ----
    float4 ga[4];
    #pragma unroll
    for (int j = 0; j < 4; ++j) {
        float4 t0 = shfl4(st[j],     src);
        float4 t1 = shfl4(st[j + 4], src);
        ga[j] = hf ? t1 : t0;
    }

    // ---------------- pass 2: top-9 of my 16 via sort8+sort8+valley-merge ----------------
    const int ebase = g * 32 + hf * 16;
    float a0=ga[0].x, a1=ga[0].y, a2=ga[0].z, a3=ga[0].w,
          a4=ga[1].x, a5=ga[1].y, a6=ga[1].z, a7=ga[1].w;
    int   ja0=ebase+0, ja1=ebase+1, ja2=ebase+2, ja3=ebase+3,
          ja4=ebase+4, ja5=ebase+5, ja6=ebase+6, ja7=ebase+7;
    float b0=ga[2].x, b1=ga[2].y, b2=ga[2].z, b3=ga[2].w,
          b4=ga[3].x, b5=ga[3].y, b6=ga[3].z, b7=ga[3].w;
    int   jb0=ebase+8,  jb1=ebase+9,  jb2=ebase+10, jb3=ebase+11,
          jb4=ebase+12, jb5=ebase+13, jb6=ebase+14, jb7=ebase+15;

    SORT8(a0,ja0,a1,ja1,a2,ja2,a3,ja3,a4,ja4,a5,ja5,a6,ja6,a7,ja7);
    SORT8(b0,jb0,b1,jb1,b2,jb2,b3,jb3,b4,jb4,b5,jb5,b6,jb6,b7,jb7);

    // valley merge of two sorted-8s -> top-9 multiset (valley), then clean
    float m0=a0, m1=a1, m2=a2, m3=a3, m4=a4, m5=a5, m6=a6, m7=a7, m8=-3e38f;
    int   n0=ja0, n1=ja1, n2=ja2, n3=ja3, n4=ja4, n5=ja5, n6=ja6, n7=ja7, n8=0;
    VMX(m1,n1,b7,jb7); VMX(m2,n2,b6,jb6); VMX(m3,n3,b5,jb5); VMX(m4,n4,b4,jb4);
    VMX(m5,n5,b3,jb3); VMX(m6,n6,b2,jb2); VMX(m7,n7,b1,jb1); VMX(m8,n8,b0,jb0);
    CLEAN9;

    // ---------------- butterfly bitonic merges: 8 lists of 9 -> global top-9 ----------------
    XMERGE_B(1);   // halves of same group
    XMERGE_B(2);   // group pairs
    XMERGE_B(4);   // all four groups

    // ---------------- fast-path result + flagB (h==0 lanes own the token) ----------------
    float w0 = m0 - bias_sh[n0], w1 = m1 - bias_sh[n1], w2 = m2 - bias_sh[n2],
          w3 = m3 - bias_sh[n3], w4 = m4 - bias_sh[n4], w5 = m5 - bias_sh[n5],
          w6 = m6 - bias_sh[n6], w7 = m7 - bias_sh[n7];
    int o0=n0,o1=n1,o2=n2,o3=n3,o4=n4,o5=n5,o6=n6,o7=n7;

    bool flagB = (h == 0) &&
                 (((m0-m1)<EPS_S)|((m1-m2)<EPS_S)|((m2-m3)<EPS_S)|((m3-m4)<EPS_S)|
                  ((m4-m5)<EPS_S)|((m5-m6)<EPS_S)|((m6-m7)<EPS_S)|((m7-m8)<EPS_S));
    if (__builtin_expect(flagB, 0)) {
        // f64 re-resolve of the 9 f32-top candidates; logits re-read from global (cold)
        double s0=-1e300,s1=-1e300,s2=-1e300,s3=-1e300,
               s4=-1e300,s5=-1e300,s6=-1e300,s7=-1e300;
        int c0=0,c1=0,c2=0,c3=0,c4=0,c5=0,c6=0,c7=0;
        int ci[9] = {n0,n1,n2,n3,n4,n5,n6,n7,n8};
        const float* lgt = logits + (size_t)token * 256;
        #pragma unroll 1
        for (int k = 0; k < 9; ++k) {
            int e = ci[k];
            double cs = dsigmoid(lgt[e]) + (double)bias_sh[e];
            DINS(cs, e);
        }
        w0=(float)(s0-(double)bias_sh[c0]); o0=c0;
        w1=(float)(s1-(double)bias_sh[c1]); o1=c1;
        w2=(float)(s2-(double)bias_sh[c2]); o2=c2;
        w3=(float)(s3-(double)bias_sh[c3]); o3=c3;
        w4=(float)(s4-(double)bias_sh[c4]); o4=c4;
        w5=(float)(s5-(double)bias_sh[c5]); o5=c5;
        w6=(float)(s6-(double)bias_sh[c6]); o6=c6;
        w7=(float)(s7-(double)bias_sh[c7]); o7=c7;
    }

    // ---------------- epilogue ----------------
    if (h == 0) {
        float sum = ((w0+w1)+(w2+w3)) + ((w4+w5)+(w6+w7));
        float scl = 2.5f / (sum + 1e-20f);
        float4 oa, ob;
        oa.x=w0*scl; oa.y=w1*scl; oa.z=w2*scl; oa.w=w3*scl;
        ob.x=w4*scl; ob.y=w5*scl; ob.z=w6*scl; ob.w=w7*scl;
        *(float4*)(out + (size_t)token*8)     = oa;
        *(float4*)(out + (size_t)token*8 + 4) = ob;
        float* oid = out + (size_t)T*8;
        float4 ia, ib;
        ia.x=(float)o0; ia.y=(float)o1; ia.z=(float)o2; ia.w=(float)o3;
        ib.x=(float)o4; ib.y=(float)o5; ib.z=(float)o6; ib.w=(float)o7;
        *(float4*)(oid + (size_t)token*8)     = ia;
        *(float4*)(oid + (size_t)token*8 + 4) = ib;
    }
}

extern "C" void kernel_launch(void* const* d_in, const int* in_sizes, int n_in,
                              void* d_out, int out_size, void* d_ws, size_t ws_size,
                              hipStream_t stream) {
    const float* logits = (const float*)d_in[0];
    const float* bias   = (const float*)d_in[1];
    float* out = (float*)d_out;
    int T = in_sizes[0] / NEXP;        // 131072
    int nblocks = T / TPB;             // 4096
    noauxtc_router_kernel<<<nblocks, THREADS, 0, stream>>>(logits, bias, out, T);
}

// Round 3
// 198.030 us; speedup vs baseline: 1.0846x; 1.0846x over previous
//
#include <hip/hip_runtime.h>
#include <math.h>

#define THREADS 256   // 8 threads per token; thread = one expert group
#define TPB 32        // tokens per block
#define NEXP 256
#define EPS_G 4.0e-6f // group-sum margins
// single-score margin is now integer: Q_EPS quanta of 2^-22 (9*2.38e-7 = 2.14e-6 >= old 2e-6)
#define Q_EPS 9u

// ---- fast f32 sigmoid: hw v_exp_f32 + fast divide ----
__device__ __forceinline__ float fsigmoid(float x) {
    float e = __expf(-x);
    return __fdividef(1.0f, 1.0f + e);
}

// ---- cheap near-exact f64 sigmoid (rare paths only): Taylor exp + NR division ----
__device__ __forceinline__ double dsigmoid(float xf) {
    xf = fminf(fmaxf(xf, -500.0f), 500.0f);
    double x = (double)xf;
    double t = x * -1.4426950408889634074;           // -x*log2(e)
    double n = floor(t + 0.5);
    int ni = (int)n;
    double u = (t - n) * 0.69314718055994530942;
    double pp = 2.08767569878680990e-9;
    pp = fma(pp, u, 2.50521083854417188e-8);
    pp = fma(pp, u, 2.75573192239858907e-7);
    pp = fma(pp, u, 2.75573192239858883e-6);
    pp = fma(pp, u, 2.48015873015873016e-5);
    pp = fma(pp, u, 1.98412698412698413e-4);
    pp = fma(pp, u, 1.38888888888888889e-3);
    pp = fma(pp, u, 8.33333333333333333e-3);
    pp = fma(pp, u, 4.16666666666666667e-2);
    pp = fma(pp, u, 1.66666666666666667e-1);
    pp = fma(pp, u, 0.5);
    pp = fma(pp, u, 1.0);
    pp = fma(pp, u, 1.0);
    double sc = __longlong_as_double((long long)(1023 + ni) << 52);
    double e = pp * sc;                              // exp(-x)
    double w = 1.0 + e;
    double y = (double)__fdividef(1.0f, (float)w);
    y = fma(y, fma(-w, y, 1.0), y);
    y = fma(y, fma(-w, y, 1.0), y);
    return y;
}

// f64 8-deep sorted insert (cold path)
#define DINS(cc, ee) do {                                                \
    double _d=(cc); int _e=(ee);                                         \
    if (_d > s7) {                                                       \
        bool _b0=_d>s0,_b1=_d>s1,_b2=_d>s2,_b3=_d>s3,_b4=_d>s4,          \
             _b5=_d>s5,_b6=_d>s6;                                        \
        s7=_b6?s6:_d;           c7=_b6?c6:_e;                            \
        s6=_b5?s5:(_b6?_d:s6);  c6=_b5?c5:(_b6?_e:c6);                   \
        s5=_b4?s4:(_b5?_d:s5);  c5=_b4?c4:(_b5?_e:c5);                   \
        s4=_b3?s3:(_b4?_d:s4);  c4=_b3?c3:(_b4?_e:c4);                   \
        s3=_b2?s2:(_b3?_d:s3);  c3=_b2?c2:(_b3?_e:c3);                   \
        s2=_b1?s1:(_b2?_d:s2);  c2=_b1?c1:(_b2?_e:c2);                   \
        s1=_b0?s0:(_b1?_d:s1);  c1=_b0?c0:(_b1?_e:c1);                   \
        s0=_b0?_d:s0;           c0=_b0?_e:c0;                            \
    } } while (0)

// ======== packed sort keys ========
// key = (u32(c*2^22 + 2^21) << 8) + (255 - expert_id)
// - u32 descending order == (score desc, id asc): exactly the reference tie-break.
// - distinct ids -> distinct keys: no ties exist inside the f32 phase at all.
// - quantum 2.38e-7; any adjacent pair within Q_EPS quanta (incl. bucket
//   collapse) fires flagB -> exact f64 re-resolve. Same semantics class as
//   the verified rounds 0-2.
// c in (-0.33, 1.33) => c*2^22+2^21 in (0.7e6, 7.7e6): positive, < 2^23,
// key < 2^31. fma rounding (ulp 0.5 there) adds <= 1 quantum, in budget.
__device__ __forceinline__ unsigned pack_key(float c, unsigned idflip) {
    unsigned q = (unsigned)fmaf(c, 4194304.0f, 2097152.0f);  // trunc, monotone
    return (q << 8) + idflip;
}

// CEU: descending compare-exchange -> v_max_u32 + v_min_u32 (2 VALU)
#define CEU(a, b) do {                                                   \
    unsigned _x=(a), _y=(b);                                             \
    (a) = _x>_y ? _x : _y; (b) = _x>_y ? _y : _x;                        \
} while (0)
// VMU: a := max(a,b) -> v_max_u32 (1 VALU)
#define VMU(a, b) do { (a) = (a)>(b) ? (a) : (b); } while (0)

// Batcher odd-even mergesort network for 8 keys, descending. 19 CE.
#define SORT8U(v0,v1,v2,v3,v4,v5,v6,v7) do {                             \
    CEU(v0,v1); CEU(v2,v3); CEU(v4,v5); CEU(v6,v7);                      \
    CEU(v0,v2); CEU(v1,v3); CEU(v4,v6); CEU(v5,v7);                      \
    CEU(v1,v2); CEU(v5,v6);                                              \
    CEU(v0,v4); CEU(v1,v5); CEU(v2,v6); CEU(v3,v7);                      \
    CEU(v2,v4); CEU(v3,v5);                                              \
    CEU(v1,v2); CEU(v3,v4); CEU(v5,v6);                                  \
} while (0)

// valley (dec-then-inc) 9-sequence in m0..m8 -> sorted descending. 13 CE.
// Same network as the round-1/2 validated cleanup.
#define CLEAN9U do {                                                     \
    CEU(m0,m8);                                                          \
    CEU(m1,m5); CEU(m2,m6); CEU(m3,m7); CEU(m4,m8);                      \
    CEU(m1,m3); CEU(m2,m4); CEU(m5,m7); CEU(m6,m8);                      \
    CEU(m1,m2); CEU(m3,m4); CEU(m5,m6); CEU(m7,m8);                      \
} while (0)

// Merge my sorted-desc 9-list with xor-partner's via the bitonic identity:
//   t[i] = max(a[i], b[8-i]) is the top-9 multiset, as a "valley" sequence.
// 9 shfls + 9 max + 13 CE.
#define XMERGE_U(d) do {                                                 \
    unsigned q0=(unsigned)__shfl_xor((int)m0,d,64),                      \
             q1=(unsigned)__shfl_xor((int)m1,d,64),                      \
             q2=(unsigned)__shfl_xor((int)m2,d,64),                      \
             q3=(unsigned)__shfl_xor((int)m3,d,64),                      \
             q4=(unsigned)__shfl_xor((int)m4,d,64),                      \
             q5=(unsigned)__shfl_xor((int)m5,d,64),                      \
             q6=(unsigned)__shfl_xor((int)m6,d,64),                      \
             q7=(unsigned)__shfl_xor((int)m7,d,64),                      \
             q8=(unsigned)__shfl_xor((int)m8,d,64);                      \
    VMU(m0,q8); VMU(m1,q7); VMU(m2,q6); VMU(m3,q5); VMU(m4,q4);          \
    VMU(m5,q3); VMU(m6,q2); VMU(m7,q1); VMU(m8,q0);                      \
    CLEAN9U;                                                             \
} while (0)

__device__ __forceinline__ float4 shfl4(float4 v, int src) {
    float4 r;
    r.x = __shfl(v.x, src, 64);
    r.y = __shfl(v.y, src, 64);
    r.z = __shfl(v.z, src, 64);
    r.w = __shfl(v.w, src, 64);
    return r;
}

// launch_bounds min-waves=4: VGPR cap 128. Round-2's (256,6) capped at 80 and
// spilled (WRITE_SIZE 41MB of scratch, VALUBusy 41%). Packed keys drop peak
// pressure to ~60-70; (256,4) guarantees no spill, and actual occupancy is
// set by the final VGPR count, not this bound.
__global__ __launch_bounds__(THREADS, 4)
void noauxtc_router_kernel(const float* __restrict__ logits,
                           const float* __restrict__ bias,
                           float* __restrict__ out,   // [T*8] weights, [T*8] ids-as-f32
                           int T)
{
    __shared__ __align__(16) float bias_sh[NEXP];      // 1 KiB — only LDS use

    const int tid   = threadIdx.x;
    const int h     = tid & 7;            // owned group (experts 32h..32h+31)
    const int p     = tid >> 3;           // token-in-block
    const int tok0  = blockIdx.x * TPB;
    const int token = tok0 + p;
    const int lane  = tid & 63;
    const int base  = lane & 56;          // first lane of this token's octet

    // ---- issue own-group loads early: one 128B line/thread, 8x b128 ----
    const float4* lg4 = (const float4*)logits;
    float4 st[8];
    #pragma unroll
    for (int k = 0; k < 8; ++k)
        st[k] = lg4[(size_t)token * 64 + h * 8 + k];

    bias_sh[tid] = bias[tid];             // THREADS == NEXP
    __syncthreads();                      // only barrier

    const float4* bias4 = (const float4*)bias_sh;

    // ---------------- pass 1: corrected scores in-place + own-group top-2 ----------------
    float g1 = -3e38f, g2 = -3e38f;       // group top-2 values (ids not needed)
    #pragma unroll
    for (int q = 0; q < 8; ++q) {
        float4 bb = bias4[h * 8 + q];     // broadcast across octets: free
        float4 c;
        c.x = fsigmoid(st[q].x) + bb.x;
        c.y = fsigmoid(st[q].y) + bb.y;
        c.z = fsigmoid(st[q].z) + bb.z;
        c.w = fsigmoid(st[q].w) + bb.w;
        st[q] = c;                        // overwrite logits with scores
        float h1 = fmaxf(c.x, c.y), l1 = fminf(c.x, c.y);
        float h2 = fmaxf(c.z, c.w), l2 = fminf(c.z, c.w);
        float t1 = fmaxf(h1, h2);
        float t2 = fmaxf(fminf(h1, h2), fmaxf(l1, l2));   // top-2 of the quad
        g2 = fmaxf(fminf(g1, t1), fmaxf(g2, t2));         // merge sorted pairs
        g1 = fmaxf(g1, t1);
    }
    float gs = g1 + g2;                   // group score = top-2 sum

    // ---------------- all 8 group scores via bpermute gather ----------------
    float gsv[8];
    #pragma unroll
    for (int g = 0; g < 8; ++g) gsv[g] = __shfl(gs, base + g, 64);

    // ---------------- top-4 groups (rank count, lower idx wins) + margin ----------------
    int selmask = 0; float val4 = 0.f, val5 = 0.f;
    #pragma unroll
    for (int a = 0; a < 8; ++a) {
        int rk = 0;
        #pragma unroll
        for (int b = 0; b < 8; ++b) {
            if (b == a) continue;
            bool beat = (b < a) ? (gsv[b] >= gsv[a]) : (gsv[b] > gsv[a]);
            rk += beat ? 1 : 0;
        }
        selmask |= (rk < 4) ? (1 << a) : 0;
        val4 = (rk == 3) ? gsv[a] : val4;
        val5 = (rk == 4) ? gsv[a] : val5;
    }

    // ---- flagA: ambiguous 4th vs 5th group -> pure-f64 re-rank (cold; logits from global) ----
    if (__builtin_expect(val4 - val5 < EPS_G, 0)) {
        // each thread: own group's f64 top-2 sum (uniform condition per octet)
        double a1 = -1e300, a2 = -1e300;
        const float* lgp = logits + (size_t)token * 256 + h * 32;
        #pragma unroll 1
        for (int k = 0; k < 32; ++k) {
            double c = dsigmoid(lgp[k]) + (double)bias_sh[h * 32 + k];
            a2 = fmax(a2, fmin(a1, c)); a1 = fmax(a1, c);
        }
        double gdo = a1 + a2;
        double gd[8];
        #pragma unroll
        for (int g = 0; g < 8; ++g) gd[g] = __shfl(gdo, base + g, 64);
        int sm = 0;
        #pragma unroll
        for (int a = 0; a < 8; ++a) {
            int rk = 0;
            #pragma unroll
            for (int b = 0; b < 8; ++b) {
                if (b == a) continue;
                bool beat = (b < a) ? (gd[b] >= gd[a]) : (gd[b] > gd[a]);
                rk += beat ? 1 : 0;
            }
            sm |= (rk < 4) ? (1 << a) : 0;
        }
        selmask = sm;
    }

    // ---------------- map thread -> (selected group, half) ----------------
    const int want = h >> 1;              // 0..3 : which selected group (ascending)
    int g = 0, cnt = 0;
    #pragma unroll
    for (int a = 0; a < 8; ++a) {
        bool s = (selmask >> a) & 1;
        g = (s && (cnt == want)) ? a : g;
        cnt += s ? 1 : 0;
    }
    const int hf  = h & 1;                // which 16-element half of the group
    const int src = base + g;             // lane holding that group's scores

    // ---- gather 16 scores via shfl (both halves; static reg indices; convergent) ----
    float4 ga[4];
    #pragma unroll
    for (int j = 0; j < 4; ++j) {
        float4 t0 = shfl4(st[j],     src);
        float4 t1 = shfl4(st[j + 4], src);
        ga[j] = hf ? t1 : t0;
    }

    // ---------------- pass 2: pack keys, top-9 of my 16 via sort8+sort8+valley ----------------
    const int ebase = g * 32 + hf * 16;
    const unsigned idf = 255u - (unsigned)ebase;   // idflip for idx 0; idx i -> idf - i

    unsigned k0=pack_key(ga[0].x, idf-0),  k1=pack_key(ga[0].y, idf-1),
             k2=pack_key(ga[0].z, idf-2),  k3=pack_key(ga[0].w, idf-3),
             k4=pack_key(ga[1].x, idf-4),  k5=pack_key(ga[1].y, idf-5),
             k6=pack_key(ga[1].z, idf-6),  k7=pack_key(ga[1].w, idf-7);
    unsigned l0=pack_key(ga[2].x, idf-8),  l1=pack_key(ga[2].y, idf-9),
             l2=pack_key(ga[2].z, idf-10), l3=pack_key(ga[2].w, idf-11),
             l4=pack_key(ga[3].x, idf-12), l5=pack_key(ga[3].y, idf-13),
             l6=pack_key(ga[3].z, idf-14), l7=pack_key(ga[3].w, idf-15);

    SORT8U(k0,k1,k2,k3,k4,k5,k6,k7);
    SORT8U(l0,l1,l2,l3,l4,l5,l6,l7);

    // valley merge of two sorted-8s -> top-9 multiset (valley), then clean
    unsigned m0=k0, m1=k1, m2=k2, m3=k3, m4=k4, m5=k5, m6=k6, m7=k7, m8=0u;
    VMU(m1,l7); VMU(m2,l6); VMU(m3,l5); VMU(m4,l4);
    VMU(m5,l3); VMU(m6,l2); VMU(m7,l1); VMU(m8,l0);
    CLEAN9U;

    // ---------------- butterfly bitonic merges: 8 lists of 9 -> global top-9 ----------------
    XMERGE_U(1);   // halves of same group
    XMERGE_U(2);   // group pairs
    XMERGE_U(4);   // all four groups

    // ---------------- unpack + fast-path result + flagB ----------------
    unsigned q0=m0>>8, q1=m1>>8, q2=m2>>8, q3=m3>>8, q4=m4>>8,
             q5=m5>>8, q6=m6>>8, q7=m7>>8, q8=m8>>8;
    int n0=255-(int)(m0&255u), n1=255-(int)(m1&255u), n2=255-(int)(m2&255u),
        n3=255-(int)(m3&255u), n4=255-(int)(m4&255u), n5=255-(int)(m5&255u),
        n6=255-(int)(m6&255u), n7=255-(int)(m7&255u), n8=255-(int)(m8&255u);

    // recovered quantized corrected scores (err <= ~1.5 quanta = 3.6e-7)
    const float QS = 2.384185791015625e-7f;  // 2^-22
    float v0=(float)q0*QS-0.5f, v1=(float)q1*QS-0.5f, v2=(float)q2*QS-0.5f,
          v3=(float)q3*QS-0.5f, v4=(float)q4*QS-0.5f, v5=(float)q5*QS-0.5f,
          v6=(float)q6*QS-0.5f, v7=(float)q7*QS-0.5f;

    float w0 = v0 - bias_sh[n0], w1 = v1 - bias_sh[n1], w2 = v2 - bias_sh[n2],
          w3 = v3 - bias_sh[n3], w4 = v4 - bias_sh[n4], w5 = v5 - bias_sh[n5],
          w6 = v6 - bias_sh[n6], w7 = v7 - bias_sh[n7];
    int o0=n0,o1=n1,o2=n2,o3=n3,o4=n4,o5=n5,o6=n6,o7=n7;

    // q-list is non-increasing (sorted by key desc), so unsigned diffs are safe.
    bool flagB = (h == 0) &&
                 ((q0-q1<Q_EPS)|(q1-q2<Q_EPS)|(q2-q3<Q_EPS)|(q3-q4<Q_EPS)|
                  (q4-q5<Q_EPS)|(q5-q6<Q_EPS)|(q6-q7<Q_EPS)|(q7-q8<Q_EPS));
    if (__builtin_expect(flagB, 0)) {
        // f64 re-resolve of the 9 f32-top candidates; logits re-read from global (cold)
        double s0=-1e300,s1=-1e300,s2=-1e300,s3=-1e300,
               s4=-1e300,s5=-1e300,s6=-1e300,s7=-1e300;
        int c0=0,c1=0,c2=0,c3=0,c4=0,c5=0,c6=0,c7=0;
        int ci[9] = {n0,n1,n2,n3,n4,n5,n6,n7,n8};
        const float* lgt = logits + (size_t)token * 256;
        #pragma unroll 1
        for (int k = 0; k < 9; ++k) {
            int e = ci[k];
            double cs = dsigmoid(lgt[e]) + (double)bias_sh[e];
            DINS(cs, e);
        }
        w0=(float)(s0-(double)bias_sh[c0]); o0=c0;
        w1=(float)(s1-(double)bias_sh[c1]); o1=c1;
        w2=(float)(s2-(double)bias_sh[c2]); o2=c2;
        w3=(float)(s3-(double)bias_sh[c3]); o3=c3;
        w4=(float)(s4-(double)bias_sh[c4]); o4=c4;
        w5=(float)(s5-(double)bias_sh[c5]); o5=c5;
        w6=(float)(s6-(double)bias_sh[c6]); o6=c6;
        w7=(float)(s7-(double)bias_sh[c7]); o7=c7;
    }

    // ---------------- epilogue ----------------
    if (h == 0) {
        float sum = ((w0+w1)+(w2+w3)) + ((w4+w5)+(w6+w7));
        float scl = 2.5f / (sum + 1e-20f);
        float4 oa, ob;
        oa.x=w0*scl; oa.y=w1*scl; oa.z=w2*scl; oa.w=w3*scl;
        ob.x=w4*scl; ob.y=w5*scl; ob.z=w6*scl; ob.w=w7*scl;
        *(float4*)(out + (size_t)token*8)     = oa;
        *(float4*)(out + (size_t)token*8 + 4) = ob;
        float* oid = out + (size_t)T*8;
        float4 ia, ib;
        ia.x=(float)o0; ia.y=(float)o1; ia.z=(float)o2; ia.w=(float)o3;
        ib.x=(float)o4; ib.y=(float)o5; ib.z=(float)o6; ib.w=(float)o7;
        *(float4*)(oid + (size_t)token*8)     = ia;
        *(float4*)(oid + (size_t)token*8 + 4) = ib;
    }
}

extern "C" void kernel_launch(void* const* d_in, const int* in_sizes, int n_in,
                              void* d_out, int out_size, void* d_ws, size_t ws_size,
                              hipStream_t stream) {
    const float* logits = (const float*)d_in[0];
    const float* bias   = (const float*)d_in[1];
    float* out = (float*)d_out;
    int T = in_sizes[0] / NEXP;        // 131072
    int nblocks = T / TPB;             // 4096
    noauxtc_router_kernel<<<nblocks, THREADS, 0, stream>>>(logits, bias, out, T);
}